// Round 1
// baseline (664.776 us; speedup 1.0000x reference)
//
#include <hip/hip_runtime.h>

// ---------------------------------------------------------------------------
// FastRCNN head: RoIPool(512 rois, C=512, 50x50 -> 7x7) + FC(25088->4096) +
// FC(4096->4096) + heads (21 / 84). All GEMMs via bf16 MFMA 16x16x32, fp32 acc.
// GEMM1 is HBM-bound on the 411MB fp32 W1 -> read it exactly once:
//   BM=256 x BN=64 tiles, split-K=2, grid 256 WGs (1/CU).
// ---------------------------------------------------------------------------

typedef __attribute__((ext_vector_type(8))) __bf16 bf16x8;
typedef __attribute__((ext_vector_type(4))) __bf16 bf16x4;
typedef __attribute__((ext_vector_type(4))) float f32x4;

#define N_ROIS 512
#define FH 50
#define FW 50
#define KK1 25088      // 512*49
#define D1 4096

#define BM 256
#define BN 64
#define BK 32

__device__ __forceinline__ void gll16(const void* g, void* l) {
  __builtin_amdgcn_global_load_lds(
      (const __attribute__((address_space(1))) void*)g,
      (__attribute__((address_space(3))) void*)l, 16, 0, 0);
}

// ---------------------------------------------------------------------------
// RoIPool: one block per roi; outputs pooled[roi][c*49 + py*7 + px] in bf16.
// Matches ref: r = trunc(roi * 1/16) (exact, pow2 scale), clip to [0,49],
// inclusive window, AdaptiveMaxPool bins s=floor(i*L/7), e=ceil((i+1)*L/7).
// ---------------------------------------------------------------------------
__global__ __launch_bounds__(256) void roipool_kernel(
    const float* __restrict__ x, const float* __restrict__ rois,
    __bf16* __restrict__ pooled) {
  const int roi = blockIdx.x;
  const float s = 0.0625f;
  const float r0 = rois[roi * 4 + 0], r1 = rois[roi * 4 + 1];
  const float r2 = rois[roi * 4 + 2], r3 = rois[roi * 4 + 3];
  int x1 = (int)(r0 * s); x1 = min(max(x1, 0), FW - 1);
  int y1 = (int)(r1 * s); y1 = min(max(y1, 0), FH - 1);
  int x2 = (int)(r2 * s); x2 = min(max(x2, 0), FW - 1);
  int y2 = (int)(r3 * s); y2 = min(max(y2, 0), FH - 1);
  const int ww = x2 - x1 + 1, hh = y2 - y1 + 1;
  __shared__ int cs[7], ce[7], rs[7], re[7];
  if (threadIdx.x < 7) {
    int i = threadIdx.x;
    cs[i] = x1 + (i * ww) / 7;
    ce[i] = x1 + ((i + 1) * ww + 6) / 7;
    rs[i] = y1 + (i * hh) / 7;
    re[i] = y1 + ((i + 1) * hh + 6) / 7;
  }
  __syncthreads();
  for (int idx = threadIdx.x; idx < KK1; idx += 256) {
    int c = idx / 49;
    int p = idx - c * 49;
    int py = p / 7, px = p - py * 7;
    const float* base = x + (size_t)c * (FH * FW);
    float m = -3.402823466e38f;
    for (int y = rs[py]; y < re[py]; ++y) {
      const float* rowp = base + y * FW;
      for (int xx = cs[px]; xx < ce[px]; ++xx) m = fmaxf(m, rowp[xx]);
    }
    pooled[(size_t)roi * KK1 + idx] = (__bf16)m;
  }
}

// ---------------------------------------------------------------------------
// GEMM: C_part[z][M][npad] = A[M,K](bf16) @ B[K,N](fp32, cvt->bf16 in-reg)
// Block: 512 thr = 8 waves (4M x 2N), wave tile 64x32, BK=32 per iter.
// A staged bf16 via global_load_lds (linear [256][32]);
// B staged fp32 via global_load_lds (linear [32][64]); B-frag = 8 strided
// ds_read_b32 + cvt (4-way bank conflict, hidden under HBM-bound loop).
// Double-buffered, m97-style (barrier drains vmcnt).
// ---------------------------------------------------------------------------
__global__ __launch_bounds__(512) void gemm_kernel(
    const __bf16* __restrict__ A, const float* __restrict__ B,
    float* __restrict__ part, int N, int K, int kslice, int npad) {
  __shared__ __bf16 A_lds[2][BM * BK];
  __shared__ float B_lds[2][BK * BN];
  const int tid = threadIdx.x;
  const int lane = tid & 63;
  const int w = tid >> 6;
  const int m0 = blockIdx.y * BM;
  const int n0 = blockIdx.x * BN;
  const int kbeg = blockIdx.z * kslice;
  const int niters = kslice / BK;
  const bool fullN = (n0 + BN) <= N;
  const int wm = w >> 1, wn = w & 1;

  f32x4 acc[4][2];
#pragma unroll
  for (int i = 0; i < 4; ++i)
#pragma unroll
    for (int j = 0; j < 2; ++j) acc[i][j] = (f32x4){0.f, 0.f, 0.f, 0.f};

  auto stage = [&](int buf, int kg) {
    // A tile: [256 rows][32 k] bf16 = 16KB -> 2 x 1KB issues per wave
#pragma unroll
    for (int i = 0; i < 2; ++i) {
      const int rA = w * 32 + i * 16;  // wave-uniform
      const __bf16* gp =
          A + (size_t)(m0 + rA + (lane >> 2)) * K + kg + (lane & 3) * 8;
      gll16((const void*)gp, (void*)&A_lds[buf][rA * BK]);
    }
    if (fullN) {
      // B tile: [32 k][64 n] fp32 = 8KB -> 1 x 1KB issue per wave
      const int rB = w * 4;  // wave-uniform
      const float* gp =
          B + (size_t)(kg + rB + (lane >> 4)) * N + n0 + (lane & 15) * 4;
      gll16((const void*)gp, (void*)&B_lds[buf][rB * BN]);
    } else {
      // guarded scalar path (small head GEMMs only)
      const int r = tid >> 4;          // 0..31
      const int c0 = (tid & 15) * 4;   // 0..60
#pragma unroll
      for (int j = 0; j < 4; ++j) {
        const int col = n0 + c0 + j;
        B_lds[buf][r * BN + c0 + j] =
            (col < N) ? B[(size_t)(kg + r) * N + col] : 0.f;
      }
    }
  };

  stage(0, kbeg);
  __syncthreads();

  for (int it = 0; it < niters; ++it) {
    const int cur = it & 1;
    if (it + 1 < niters) stage(cur ^ 1, kbeg + (it + 1) * BK);

    // A fragments: 4 x ds_read_b128, conflict-free (full 1KB coverage / 16 rows)
    bf16x8 af[4];
#pragma unroll
    for (int mf = 0; mf < 4; ++mf) {
      const int row = wm * 64 + mf * 16 + (lane & 15);
      af[mf] = *(const bf16x8*)&A_lds[cur][row * BK + (lane >> 4) * 8];
    }
    // B fragments: 8 strided fp32 reads each + cvt to bf16
    bf16x8 bf[2];
    const int ks0 = (lane >> 4) * 8;
#pragma unroll
    for (int nf = 0; nf < 2; ++nf) {
      const int col = wn * 32 + nf * 16 + (lane & 15);
      bf16x8 t;
#pragma unroll
      for (int e = 0; e < 8; ++e)
        t[e] = (__bf16)B_lds[cur][(ks0 + e) * BN + col];
      bf[nf] = t;
    }
#pragma unroll
    for (int mf = 0; mf < 4; ++mf)
#pragma unroll
      for (int nf = 0; nf < 2; ++nf)
        acc[mf][nf] = __builtin_amdgcn_mfma_f32_16x16x32_bf16(
            af[mf], bf[nf], acc[mf][nf], 0, 0, 0);
    __syncthreads();
  }

  // epilogue: C/D layout col=lane&15, row=(lane>>4)*4+r (guide-verified)
  const int r0 = (lane >> 4) * 4;
  const int cN = lane & 15;
  float* pbase = part + (size_t)blockIdx.z * 512 * npad;
#pragma unroll
  for (int mf = 0; mf < 4; ++mf)
#pragma unroll
    for (int nf = 0; nf < 2; ++nf) {
      const int col = n0 + wn * 32 + nf * 16 + cN;
#pragma unroll
      for (int r = 0; r < 4; ++r) {
        const int row = m0 + wm * 64 + mf * 16 + r0 + r;
        pbase[(size_t)row * npad + col] = acc[mf][nf][r];
      }
    }
}

// sum split-K partials + bias, relu, -> bf16 activations [512][4096]
__global__ __launch_bounds__(256) void reduce_relu_kernel(
    const float* __restrict__ part, const float* __restrict__ bias,
    __bf16* __restrict__ out, int nsplit) {
  const int idx = blockIdx.x * 256 + threadIdx.x;
  const int flat = idx * 4;
  if (flat >= 512 * 4096) return;
  f32x4 s = *(const f32x4*)(part + flat);
  for (int sp = 1; sp < nsplit; ++sp)
    s += *(const f32x4*)(part + (size_t)sp * (512 * 4096) + flat);
  const f32x4 b = *(const f32x4*)(bias + (flat & 4095));
  s += b;
  bf16x4 o;
#pragma unroll
  for (int i = 0; i < 4; ++i) {
    float v = s[i] > 0.f ? s[i] : 0.f;
    o[i] = (__bf16)v;
  }
  *(bf16x4*)(out + flat) = o;
}

// final: sum 16 split-K partials + bias -> d_out fp32 (cls then reg, flat)
__global__ __launch_bounds__(256) void reduce_out_kernel(
    const float* __restrict__ pc, const float* __restrict__ pr,
    const float* __restrict__ bcls, const float* __restrict__ breg,
    float* __restrict__ out) {
  const int gid = blockIdx.x * 256 + threadIdx.x;
  if (gid >= 512 * 105) return;
  if (gid < 512 * 21) {
    const int m = gid / 21, j = gid - m * 21;
    float s = bcls[j];
#pragma unroll
    for (int sp = 0; sp < 16; ++sp) s += pc[(size_t)sp * 512 * 64 + m * 64 + j];
    out[gid] = s;
  } else {
    const int g = gid - 512 * 21;
    const int m = g / 84, j = g - m * 84;
    float s = breg[j];
#pragma unroll
    for (int sp = 0; sp < 16; ++sp) s += pr[(size_t)sp * 512 * 128 + m * 128 + j];
    out[gid] = s;
  }
}

extern "C" void kernel_launch(void* const* d_in, const int* in_sizes, int n_in,
                              void* d_out, int out_size, void* d_ws, size_t ws_size,
                              hipStream_t stream) {
  (void)in_sizes; (void)n_in; (void)out_size; (void)ws_size;
  const float* x    = (const float*)d_in[0];
  // d_in[1] = img (only shape matters; 800x800 hardcoded -> scale 1/16)
  const float* rois = (const float*)d_in[2];
  const float* W1   = (const float*)d_in[3];
  const float* b1   = (const float*)d_in[4];
  const float* W2   = (const float*)d_in[5];
  const float* b2   = (const float*)d_in[6];
  const float* Wcls = (const float*)d_in[7];
  const float* bcls = (const float*)d_in[8];
  const float* Wreg = (const float*)d_in[9];
  const float* breg = (const float*)d_in[10];
  float* out = (float*)d_out;

  // workspace layout (total ~48.5 MiB)
  char* ws = (char*)d_ws;
  __bf16* pooled = (__bf16*)ws;                       // 512*25088*2 = 25,690,112
  size_t off = (size_t)512 * KK1 * 2;
  __bf16* f1 = (__bf16*)(ws + off); off += (size_t)512 * D1 * 2;   // 4 MiB
  __bf16* f2 = (__bf16*)(ws + off); off += (size_t)512 * D1 * 2;   // 4 MiB
  float* part = (float*)(ws + off);                   // 16 MiB (max of uses)
  float* pcls = part;                                 // 16*512*64 fp32
  float* preg = part + (size_t)16 * 512 * 64;         // 16*512*128 fp32

  // 1) RoIPool -> pooled bf16 [512, 25088]
  roipool_kernel<<<N_ROIS, 256, 0, stream>>>(x, rois, pooled);

  // 2) GEMM1: [512,25088] @ W1[25088,4096], split-K=2 (W1 read exactly once)
  gemm_kernel<<<dim3(64, 2, 2), 512, 0, stream>>>(pooled, W1, part,
                                                  4096, KK1, 12544, 4096);
  reduce_relu_kernel<<<2048, 256, 0, stream>>>(part, b1, f1, 2);

  // 3) GEMM2: [512,4096] @ W2[4096,4096], split-K=2
  gemm_kernel<<<dim3(64, 2, 2), 512, 0, stream>>>(f1, W2, part,
                                                  4096, 4096, 2048, 4096);
  reduce_relu_kernel<<<2048, 256, 0, stream>>>(part, b2, f2, 2);

  // 4) heads: Wcls [4096,21], Wreg [4096,84], split-K=16
  gemm_kernel<<<dim3(1, 2, 16), 512, 0, stream>>>(f2, Wcls, pcls,
                                                  21, 4096, 256, 64);
  gemm_kernel<<<dim3(2, 2, 16), 512, 0, stream>>>(f2, Wreg, preg,
                                                  84, 4096, 256, 128);
  reduce_out_kernel<<<(512 * 105 + 255) / 256, 256, 0, stream>>>(
      pcls, preg, bcls, breg, out);
}

// Round 2
// 600.174 us; speedup vs baseline: 1.1076x; 1.1076x over previous
//
#include <hip/hip_runtime.h>

// ---------------------------------------------------------------------------
// FastRCNN head: RoIPool(512 rois, C=512, 50x50 -> 7x7) + FC(25088->4096) +
// FC(4096->4096) + heads (21 / 84). GEMMs via bf16 MFMA 16x16x32, fp32 acc.
// R2: BM=512 (weights read exactly once), split-K=8 (2 blocks/CU), both-sides
// XOR swizzle on A and B LDS (conflict-free frag reads), bf16 partials.
// ---------------------------------------------------------------------------

typedef __attribute__((ext_vector_type(8))) __bf16 bf16x8;
typedef __attribute__((ext_vector_type(4))) __bf16 bf16x4;
typedef __attribute__((ext_vector_type(4))) float f32x4;

#define N_ROIS 512
#define FH 50
#define FW 50
#define KK1 25088      // 512*49
#define D1 4096

#define BM 512
#define BN 64
#define BK 32

__device__ __forceinline__ void gll16(const void* g, void* l) {
  __builtin_amdgcn_global_load_lds(
      (const __attribute__((address_space(1))) void*)g,
      (__attribute__((address_space(3))) void*)l, 16, 0, 0);
}

// ---------------------------------------------------------------------------
// RoIPool (unchanged from R1, validated)
// ---------------------------------------------------------------------------
__global__ __launch_bounds__(256) void roipool_kernel(
    const float* __restrict__ x, const float* __restrict__ rois,
    __bf16* __restrict__ pooled) {
  const int roi = blockIdx.x;
  const float s = 0.0625f;
  const float r0 = rois[roi * 4 + 0], r1 = rois[roi * 4 + 1];
  const float r2 = rois[roi * 4 + 2], r3 = rois[roi * 4 + 3];
  int x1 = (int)(r0 * s); x1 = min(max(x1, 0), FW - 1);
  int y1 = (int)(r1 * s); y1 = min(max(y1, 0), FH - 1);
  int x2 = (int)(r2 * s); x2 = min(max(x2, 0), FW - 1);
  int y2 = (int)(r3 * s); y2 = min(max(y2, 0), FH - 1);
  const int ww = x2 - x1 + 1, hh = y2 - y1 + 1;
  __shared__ int cs[7], ce[7], rs[7], re[7];
  if (threadIdx.x < 7) {
    int i = threadIdx.x;
    cs[i] = x1 + (i * ww) / 7;
    ce[i] = x1 + ((i + 1) * ww + 6) / 7;
    rs[i] = y1 + (i * hh) / 7;
    re[i] = y1 + ((i + 1) * hh + 6) / 7;
  }
  __syncthreads();
  for (int idx = threadIdx.x; idx < KK1; idx += 256) {
    int c = idx / 49;
    int p = idx - c * 49;
    int py = p / 7, px = p - py * 7;
    const float* base = x + (size_t)c * (FH * FW);
    float m = -3.402823466e38f;
    for (int y = rs[py]; y < re[py]; ++y) {
      const float* rowp = base + y * FW;
      for (int xx = cs[px]; xx < ce[px]; ++xx) m = fmaxf(m, rowp[xx]);
    }
    pooled[(size_t)roi * KK1 + idx] = (__bf16)m;
  }
}

// ---------------------------------------------------------------------------
// GEMM: part[z][512][npad] = A[512,K](bf16) @ B[K,N](fp32 -> bf16 in-reg)
// 8 waves; wave = 64 rows x 64 cols; BK=32. LDS 80KB -> 2 blocks/CU.
// A LDS [512][32] bf16, swizzle: 16B slot = ks ^ ((row^(row>>2))&3)  (2-way)
// B LDS [32][64] f32, swizzle: elem col ^= 16*((row>>3)&1)           (2-way)
// Both staged linearly by global_load_lds with pre-swizzled global source.
// ---------------------------------------------------------------------------
template <typename OutT>
__global__ __launch_bounds__(512, 4) void gemm_kernel(
    const __bf16* __restrict__ A, const float* __restrict__ B,
    OutT* __restrict__ part, int N, int K, int kslice, int npad) {
  __shared__ __bf16 A_lds[2][BM * BK];   // 2 x 32KB
  __shared__ float B_lds[2][BK * BN];    // 2 x 8KB
  const int tid = threadIdx.x;
  const int lane = tid & 63;
  const int w = tid >> 6;
  const int n0 = blockIdx.x * BN;
  const int kbeg = blockIdx.z * kslice;
  const int niters = kslice / BK;
  const bool fullN = (n0 + BN) <= N;

  f32x4 acc[4][4];
#pragma unroll
  for (int i = 0; i < 4; ++i)
#pragma unroll
    for (int j = 0; j < 4; ++j) acc[i][j] = (f32x4){0.f, 0.f, 0.f, 0.f};

  // A staging: per-lane fetch swizzle. lane l writes linear slot (l&3) of
  // row rA+(l>>2); that slot holds global ks = (l&3) ^ sw(row),
  // sw(row) = (row ^ (row>>2)) & 3. Here row&3=(l>>2)&3, (row>>2)&3=(l>>4)&3.
  const int aswz = (lane & 3) ^ (((lane >> 2) & 3) ^ ((lane >> 4) & 3));
  const int arow = lane >> 2;
  // B staging: lane l -> row rB+(l>>4), 16B slot (l&15); fetch global colblk
  // = (l&15) ^ (((row>>3)&1)<<2).
  const int brlo = lane >> 4;
  const int bslot = lane & 15;

  auto stage = [&](int buf, int kg) {
#pragma unroll
    for (int i = 0; i < 4; ++i) {
      const int rA = w * 64 + i * 16;  // wave-uniform
      const __bf16* gp = A + (size_t)(rA + arow) * K + kg + aswz * 8;
      gll16((const void*)gp, (void*)&A_lds[buf][rA * BK]);
    }
    if (fullN) {
      const int rB = w * 4;  // wave-uniform
      const int row = rB + brlo;
      const int cb = bslot ^ (((row >> 3) & 1) << 2);
      const float* gp = B + (size_t)(kg + row) * N + n0 + cb * 4;
      gll16((const void*)gp, (void*)&B_lds[buf][rB * BN]);
    } else {
      // guarded scalar path (head GEMMs only), swizzled store
      const int r = tid >> 4;          // 0..31
      const int c0 = (tid & 15) * 4;   // 0..60
      const int g16 = ((r >> 3) & 1) << 4;
#pragma unroll
      for (int j = 0; j < 4; ++j) {
        const int col = n0 + c0 + j;
        B_lds[buf][r * BN + ((c0 + j) ^ g16)] =
            (col < N) ? B[(size_t)(kg + r) * N + col] : 0.f;
      }
    }
  };

  stage(0, kbeg);
  __syncthreads();

  const int fr = lane & 15;                       // frag row/col within 16
  const int ks = lane >> 4;                       // k-slot 0..3
  const int aslot = ks ^ ((fr & 3) ^ ((fr >> 2) & 3));  // A read swizzle
  const int bswz = (ks & 1) << 4;                 // B read swizzle (elem xor)

  for (int it = 0; it < niters; ++it) {
    const int cur = it & 1;
    if (it + 1 < niters) stage(cur ^ 1, kbeg + (it + 1) * BK);

    bf16x8 af[4];
#pragma unroll
    for (int mf = 0; mf < 4; ++mf) {
      const int row = w * 64 + mf * 16 + fr;
      af[mf] = *(const bf16x8*)&A_lds[cur][row * BK + aslot * 8];
    }
#pragma unroll
    for (int nf = 0; nf < 4; ++nf) {
      const int c = (nf * 16 + fr) ^ bswz;
      bf16x8 bfr;
#pragma unroll
      for (int e = 0; e < 8; ++e)
        bfr[e] = (__bf16)B_lds[cur][(ks * 8 + e) * BN + c];
#pragma unroll
      for (int mf = 0; mf < 4; ++mf)
        acc[mf][nf] = __builtin_amdgcn_mfma_f32_16x16x32_bf16(
            af[mf], bfr, acc[mf][nf], 0, 0, 0);
    }
    __syncthreads();
  }

  // C/D layout: col = lane&15, row = (lane>>4)*4 + r
  const int r0 = ks * 4;
  OutT* pbase = part + (size_t)blockIdx.z * 512 * npad;
#pragma unroll
  for (int mf = 0; mf < 4; ++mf)
#pragma unroll
    for (int nf = 0; nf < 4; ++nf) {
      const int col = n0 + nf * 16 + fr;
#pragma unroll
      for (int r = 0; r < 4; ++r) {
        const int row = w * 64 + mf * 16 + r0 + r;
        pbase[(size_t)row * npad + col] = (OutT)acc[mf][nf][r];
      }
    }
}

// sum bf16 split-K partials + bias, relu -> bf16 activations [512][4096]
__global__ __launch_bounds__(256) void reduce_relu_kernel(
    const __bf16* __restrict__ part, const float* __restrict__ bias,
    __bf16* __restrict__ out, int nsplit) {
  const int idx = blockIdx.x * 256 + threadIdx.x;
  const int flat = idx * 8;
  if (flat >= 512 * 4096) return;
  float s[8];
#pragma unroll
  for (int j = 0; j < 8; ++j) s[j] = 0.f;
  for (int sp = 0; sp < nsplit; ++sp) {
    bf16x8 v = *(const bf16x8*)(part + (size_t)sp * (512 * 4096) + flat);
#pragma unroll
    for (int j = 0; j < 8; ++j) s[j] += (float)v[j];
  }
  const int nb = flat & 4095;
  bf16x8 o;
#pragma unroll
  for (int j = 0; j < 8; ++j) {
    float v = s[j] + bias[nb + j];
    o[j] = (__bf16)(v > 0.f ? v : 0.f);
  }
  *(bf16x8*)(out + flat) = o;
}

// final: sum 16 split-K fp32 partials + bias -> d_out fp32 (cls then reg)
__global__ __launch_bounds__(256) void reduce_out_kernel(
    const float* __restrict__ pc, const float* __restrict__ pr,
    const float* __restrict__ bcls, const float* __restrict__ breg,
    float* __restrict__ out) {
  const int gid = blockIdx.x * 256 + threadIdx.x;
  if (gid >= 512 * 105) return;
  if (gid < 512 * 21) {
    const int m = gid / 21, j = gid - m * 21;
    float s = bcls[j];
#pragma unroll
    for (int sp = 0; sp < 16; ++sp) s += pc[(size_t)sp * 512 * 64 + m * 64 + j];
    out[gid] = s;
  } else {
    const int g = gid - 512 * 21;
    const int m = g / 84, j = g - m * 84;
    float s = breg[j];
#pragma unroll
    for (int sp = 0; sp < 16; ++sp) s += pr[(size_t)sp * 512 * 128 + m * 128 + j];
    out[gid] = s;
  }
}

extern "C" void kernel_launch(void* const* d_in, const int* in_sizes, int n_in,
                              void* d_out, int out_size, void* d_ws, size_t ws_size,
                              hipStream_t stream) {
  (void)in_sizes; (void)n_in; (void)out_size;
  const float* x    = (const float*)d_in[0];
  const float* rois = (const float*)d_in[2];
  const float* W1   = (const float*)d_in[3];
  const float* b1   = (const float*)d_in[4];
  const float* W2   = (const float*)d_in[5];
  const float* b2   = (const float*)d_in[6];
  const float* Wcls = (const float*)d_in[7];
  const float* bcls = (const float*)d_in[8];
  const float* Wreg = (const float*)d_in[9];
  const float* breg = (const float*)d_in[10];
  float* out = (float*)d_out;

  const size_t pooled_b = (size_t)512 * KK1 * 2;        // 25,690,112
  const size_t act_b = (size_t)512 * D1 * 2;            // 4 MiB
  // split-K count chosen from ws_size (host-side, deterministic)
  const size_t need8 = pooled_b + (size_t)8 * act_b + 2 * act_b;  // ~67.3 MB
  const int ns = (ws_size >= need8) ? 8 : 2;

  char* ws = (char*)d_ws;
  __bf16* pooled = (__bf16*)ws;
  __bf16* part1 = (__bf16*)(ws + pooled_b);             // ns * 4MiB (bf16)
  __bf16* f1 = (__bf16*)(ws + pooled_b + (size_t)ns * act_b);
  __bf16* f2 = (__bf16*)(ws + pooled_b + (size_t)ns * act_b + act_b);
  __bf16* part2 = (__bf16*)ws;                          // alias dead pooled
  float* pcls = (float*)ws;                             // alias (heads phase)
  float* preg = (float*)(ws + (size_t)16 * 512 * 64 * 4);

  // 1) RoIPool -> pooled bf16 [512, 25088]
  roipool_kernel<<<N_ROIS, 256, 0, stream>>>(x, rois, pooled);

  // 2) GEMM1: pooled @ W1[25088,4096]; W1 read exactly once
  gemm_kernel<__bf16><<<dim3(64, 1, ns), 512, 0, stream>>>(
      pooled, W1, part1, 4096, KK1, KK1 / ns, 4096);
  reduce_relu_kernel<<<1024, 256, 0, stream>>>(part1, b1, f1, ns);

  // 3) GEMM2: f1 @ W2[4096,4096]
  gemm_kernel<__bf16><<<dim3(64, 1, ns), 512, 0, stream>>>(
      f1, W2, part2, 4096, 4096, 4096 / ns, 4096);
  reduce_relu_kernel<<<1024, 256, 0, stream>>>(part2, b2, f2, ns);

  // 4) heads: Wcls [4096,21], Wreg [4096,84], split-K=16, fp32 partials
  gemm_kernel<float><<<dim3(1, 1, 16), 512, 0, stream>>>(
      f2, Wcls, pcls, 21, 4096, 256, 64);
  gemm_kernel<float><<<dim3(2, 1, 16), 512, 0, stream>>>(
      f2, Wreg, preg, 84, 4096, 256, 128);
  reduce_out_kernel<<<(512 * 105 + 255) / 256, 256, 0, stream>>>(
      pcls, preg, bcls, breg, out);
}

// Round 3
// 585.792 us; speedup vs baseline: 1.1348x; 1.0246x over previous
//
#include <hip/hip_runtime.h>

// ---------------------------------------------------------------------------
// FastRCNN head: RoIPool + FC(25088->4096) + FC(4096->4096) + heads (21/84).
// R3: XCD z-pinning (all blocks of a K-window on one XCD -> A re-reads are L2
// hits), pair-packed reg-staged B (frag read = 1 ds_read_b128 per nf instead
// of 8 ds_read_b32), early B-load issue (latency hidden under MFMA).
// ---------------------------------------------------------------------------

typedef __attribute__((ext_vector_type(8))) __bf16 bf16x8;
typedef __attribute__((ext_vector_type(4))) float f32x4;

#define N_ROIS 512
#define FH 50
#define FW 50
#define KK1 25088      // 512*49
#define D1 4096

#define BM 512
#define BN 64
#define BK 32

__device__ __forceinline__ void gll16(const void* g, void* l) {
  __builtin_amdgcn_global_load_lds(
      (const __attribute__((address_space(1))) void*)g,
      (__attribute__((address_space(3))) void*)l, 16, 0, 0);
}

// ---------------------------------------------------------------------------
// RoIPool (validated R1/R2)
// ---------------------------------------------------------------------------
__global__ __launch_bounds__(256) void roipool_kernel(
    const float* __restrict__ x, const float* __restrict__ rois,
    __bf16* __restrict__ pooled) {
  const int roi = blockIdx.x;
  const float s = 0.0625f;
  const float r0 = rois[roi * 4 + 0], r1 = rois[roi * 4 + 1];
  const float r2 = rois[roi * 4 + 2], r3 = rois[roi * 4 + 3];
  int x1 = (int)(r0 * s); x1 = min(max(x1, 0), FW - 1);
  int y1 = (int)(r1 * s); y1 = min(max(y1, 0), FH - 1);
  int x2 = (int)(r2 * s); x2 = min(max(x2, 0), FW - 1);
  int y2 = (int)(r3 * s); y2 = min(max(y2, 0), FH - 1);
  const int ww = x2 - x1 + 1, hh = y2 - y1 + 1;
  __shared__ int cs[7], ce[7], rs[7], re[7];
  if (threadIdx.x < 7) {
    int i = threadIdx.x;
    cs[i] = x1 + (i * ww) / 7;
    ce[i] = x1 + ((i + 1) * ww + 6) / 7;
    rs[i] = y1 + (i * hh) / 7;
    re[i] = y1 + ((i + 1) * hh + 6) / 7;
  }
  __syncthreads();
  for (int idx = threadIdx.x; idx < KK1; idx += 256) {
    int c = idx / 49;
    int p = idx - c * 49;
    int py = p / 7, px = p - py * 7;
    const float* base = x + (size_t)c * (FH * FW);
    float m = -3.402823466e38f;
    for (int y = rs[py]; y < re[py]; ++y) {
      const float* rowp = base + y * FW;
      for (int xx = cs[px]; xx < ce[px]; ++xx) m = fmaxf(m, rowp[xx]);
    }
    pooled[(size_t)roi * KK1 + idx] = (__bf16)m;
  }
}

// ---------------------------------------------------------------------------
// GEMM: part[z][512][npad] = A[512,K](bf16) @ B[K,N](fp32 -> bf16 at stage)
// Flattened grid: z = bid & ((1<<zshift)-1)  (-> XCD = bid%8 pins K-windows),
// n0 = (bid >> zshift) * 64.
// A: global_load_lds, [512][32] bf16, 16B-slot swizzle (validated R2).
// B: reg-staged pair-pack. Thread loads 2x float2 (rows 2kp,2kp+1), packs
//    bf16 (k,k+1) pairs, ds_write into Bu[c][slot]: u32 idx =
//    c*16 + ((kp>>2) ^ ((c>>2)&3))*4 + (kp&3). Frag read: 1 ds_read_b128/nf.
// ---------------------------------------------------------------------------
template <typename OutT>
__global__ __launch_bounds__(512, 4) void gemm_kernel(
    const __bf16* __restrict__ A, const float* __restrict__ B,
    OutT* __restrict__ part, int N, int K, int kslice, int npad, int zshift) {
  __shared__ __bf16 A_lds[2][BM * BK];       // 2 x 32KB
  __shared__ unsigned int Bu[2][(BK / 2) * BN];  // 2 x 4KB (bf16 pairs)
  const int tid = threadIdx.x;
  const int lane = tid & 63;
  const int w = tid >> 6;
  const int bid = blockIdx.x;
  const int z = bid & ((1 << zshift) - 1);
  const int n0 = (bid >> zshift) * BN;
  const int kbeg = z * kslice;
  const int niters = kslice / BK;
  const bool fullN = (n0 + BN) <= N;

  f32x4 acc[4][4];
#pragma unroll
  for (int i = 0; i < 4; ++i)
#pragma unroll
    for (int j = 0; j < 4; ++j) acc[i][j] = (f32x4){0.f, 0.f, 0.f, 0.f};

  // A staging swizzle (R2-validated): lane l -> row l>>2, 16B slot
  // (l&3) ^ sw(row), sw(row)=(row^(row>>2))&3
  const int aswz = (lane & 3) ^ (((lane >> 2) & 3) ^ ((lane >> 4) & 3));
  const int arow = lane >> 2;

  // B staging: thread -> k-pair kp = tid>>5 (rows 2kp,2kp+1), cols bc0,bc0+1
  const int bkp = tid >> 5;           // 0..15
  const int bc0 = (tid & 31) * 2;     // 0..62 (even)
  const int bg = bkp >> 2, be = bkp & 3;
  const int bidx0 = bc0 * 16 + ((bg ^ ((bc0 >> 2) & 3)) * 4 + be);

  float2 bl0, bl1;
  auto loadB = [&](int kg) {
    if (fullN) {
      const float* g0 = B + (size_t)(kg + 2 * bkp) * N + n0 + bc0;
      bl0 = *(const float2*)g0;
      bl1 = *(const float2*)(g0 + N);
    } else {
      const float* r0 = B + (size_t)(kg + 2 * bkp) * N;
      const float* r1 = r0 + N;
      const int c0 = n0 + bc0, c1 = c0 + 1;
      bl0.x = (c0 < N) ? r0[c0] : 0.f;
      bl0.y = (c1 < N) ? r0[c1] : 0.f;
      bl1.x = (c0 < N) ? r1[c0] : 0.f;
      bl1.y = (c1 < N) ? r1[c1] : 0.f;
    }
  };
  auto writeB = [&](int buf) {
    union { __bf16 h[2]; unsigned int u; } p0, p1;
    p0.h[0] = (__bf16)bl0.x; p0.h[1] = (__bf16)bl1.x;  // lo = even k
    p1.h[0] = (__bf16)bl0.y; p1.h[1] = (__bf16)bl1.y;
    Bu[buf][bidx0] = p0.u;
    Bu[buf][bidx0 + 16] = p1.u;
  };
  auto stageA = [&](int buf, int kg) {
#pragma unroll
    for (int i = 0; i < 4; ++i) {
      const int rA = w * 64 + i * 16;  // wave-uniform
      const __bf16* gp = A + (size_t)(rA + arow) * K + kg + aswz * 8;
      gll16((const void*)gp, (void*)&A_lds[buf][rA * BK]);
    }
  };

  // prologue
  loadB(kbeg);
  stageA(0, kbeg);
  writeB(0);
  __syncthreads();

  const int fr = lane & 15;
  const int ks = lane >> 4;
  const int aslot = ks ^ ((fr & 3) ^ ((fr >> 2) & 3));
  const int bslot = ks ^ ((fr >> 2) & 3);  // (c>>2)&3 == (fr>>2)&3

  for (int it = 0; it < niters; ++it) {
    const int cur = it & 1;
    const bool more = (it + 1) < niters;
    if (more) {
      loadB(kbeg + (it + 1) * BK);            // issued first (oldest vmem)
      stageA(cur ^ 1, kbeg + (it + 1) * BK);  // 4 gll16 after -> cvt waits vmcnt(4)
    }
    bf16x8 af[4];
#pragma unroll
    for (int mf = 0; mf < 4; ++mf) {
      const int row = w * 64 + mf * 16 + fr;
      af[mf] = *(const bf16x8*)&A_lds[cur][row * BK + aslot * 8];
    }
#pragma unroll
    for (int nf = 0; nf < 4; ++nf) {
      const int c = nf * 16 + fr;
      bf16x8 bfr = *(const bf16x8*)((const char*)&Bu[cur][0] + c * 64 + bslot * 16);
#pragma unroll
      for (int mf = 0; mf < 4; ++mf)
        acc[mf][nf] = __builtin_amdgcn_mfma_f32_16x16x32_bf16(
            af[mf], bfr, acc[mf][nf], 0, 0, 0);
    }
    if (more) writeB(cur ^ 1);  // cvt+2x ds_write after MFMA, before barrier
    __syncthreads();
  }

  // C/D layout: col = lane&15, row = (lane>>4)*4 + r
  const int r0 = ks * 4;
  OutT* pbase = part + (size_t)z * 512 * npad;
#pragma unroll
  for (int mf = 0; mf < 4; ++mf)
#pragma unroll
    for (int nf = 0; nf < 4; ++nf) {
      const int col = n0 + nf * 16 + fr;
#pragma unroll
      for (int r = 0; r < 4; ++r) {
        const int row = w * 64 + mf * 16 + r0 + r;
        pbase[(size_t)row * npad + col] = (OutT)acc[mf][nf][r];
      }
    }
}

// sum bf16 split-K partials + bias, relu -> bf16 activations [512][4096]
__global__ __launch_bounds__(256) void reduce_relu_kernel(
    const __bf16* __restrict__ part, const float* __restrict__ bias,
    __bf16* __restrict__ out, int nsplit) {
  const int idx = blockIdx.x * 256 + threadIdx.x;
  const int flat = idx * 8;
  if (flat >= 512 * 4096) return;
  float s[8];
#pragma unroll
  for (int j = 0; j < 8; ++j) s[j] = 0.f;
  for (int sp = 0; sp < nsplit; ++sp) {
    bf16x8 v = *(const bf16x8*)(part + (size_t)sp * (512 * 4096) + flat);
#pragma unroll
    for (int j = 0; j < 8; ++j) s[j] += (float)v[j];
  }
  const int nb = flat & 4095;
  bf16x8 o;
#pragma unroll
  for (int j = 0; j < 8; ++j) {
    float v = s[j] + bias[nb + j];
    o[j] = (__bf16)(v > 0.f ? v : 0.f);
  }
  *(bf16x8*)(out + flat) = o;
}

// final: sum split-K fp32 partials + bias -> d_out fp32 (cls then reg)
__global__ __launch_bounds__(256) void reduce_out_kernel(
    const float* __restrict__ pc, const float* __restrict__ pr,
    const float* __restrict__ bcls, const float* __restrict__ breg,
    float* __restrict__ out, int nsplit) {
  const int gid = blockIdx.x * 256 + threadIdx.x;
  if (gid >= 512 * 105) return;
  if (gid < 512 * 21) {
    const int m = gid / 21, j = gid - m * 21;
    float s = bcls[j];
    for (int sp = 0; sp < nsplit; ++sp)
      s += pc[(size_t)sp * 512 * 64 + m * 64 + j];
    out[gid] = s;
  } else {
    const int g = gid - 512 * 21;
    const int m = g / 84, j = g - m * 84;
    float s = breg[j];
    for (int sp = 0; sp < nsplit; ++sp)
      s += pr[(size_t)sp * 512 * 128 + m * 128 + j];
    out[gid] = s;
  }
}

extern "C" void kernel_launch(void* const* d_in, const int* in_sizes, int n_in,
                              void* d_out, int out_size, void* d_ws, size_t ws_size,
                              hipStream_t stream) {
  (void)in_sizes; (void)n_in; (void)out_size;
  const float* x    = (const float*)d_in[0];
  const float* rois = (const float*)d_in[2];
  const float* W1   = (const float*)d_in[3];
  const float* b1   = (const float*)d_in[4];
  const float* W2   = (const float*)d_in[5];
  const float* b2   = (const float*)d_in[6];
  const float* Wcls = (const float*)d_in[7];
  const float* bcls = (const float*)d_in[8];
  const float* Wreg = (const float*)d_in[9];
  const float* breg = (const float*)d_in[10];
  float* out = (float*)d_out;

  const size_t pooled_b = (size_t)512 * KK1 * 2;        // 25,690,112
  const size_t act_b = (size_t)512 * D1 * 2;            // 4 MiB
  const size_t need8 = pooled_b + (size_t)8 * act_b + 2 * act_b;  // ~69 MB
  const int ns = (ws_size >= need8) ? 8 : 2;            // R2 proved ns=8 fits
  const int zshift = (ns == 8) ? 3 : 1;

  char* ws = (char*)d_ws;
  __bf16* pooled = (__bf16*)ws;
  __bf16* part1 = (__bf16*)(ws + pooled_b);             // ns * 4MiB
  __bf16* f1 = (__bf16*)(ws + pooled_b + (size_t)ns * act_b);
  __bf16* f2 = (__bf16*)(ws + pooled_b + (size_t)ns * act_b + act_b);
  __bf16* part2 = (__bf16*)ws;                          // alias dead pooled+part1
  float* pcls = (float*)ws;                             // heads phase aliases
  float* preg = (float*)(ws + (size_t)64 * 512 * 64 * 4);  // +8.4MB

  // 1) RoIPool -> pooled bf16 [512, 25088]
  roipool_kernel<<<N_ROIS, 256, 0, stream>>>(x, rois, pooled);

  // 2) GEMM1: pooled @ W1[25088,4096]; W1 read exactly once; z-pinned XCDs
  gemm_kernel<__bf16><<<64 * ns, 512, 0, stream>>>(
      pooled, W1, part1, 4096, KK1, KK1 / ns, 4096, zshift);
  reduce_relu_kernel<<<1024, 256, 0, stream>>>(part1, b1, f1, ns);

  // 3) GEMM2: f1 @ W2[4096,4096]
  gemm_kernel<__bf16><<<64 * ns, 512, 0, stream>>>(
      f1, W2, part2, 4096, 4096, 4096 / ns, 4096, zshift);
  reduce_relu_kernel<<<1024, 256, 0, stream>>>(part2, b2, f2, ns);

  // 4) heads: split-K=64 (zshift 6): grids 64 / 128 blocks
  gemm_kernel<float><<<1 * 64, 512, 0, stream>>>(
      f2, Wcls, pcls, 21, 4096, 64, 64, 6);
  gemm_kernel<float><<<2 * 64, 512, 0, stream>>>(
      f2, Wreg, preg, 84, 4096, 64, 128, 6);
  reduce_out_kernel<<<(512 * 105 + 255) / 256, 256, 0, stream>>>(
      pcls, preg, bcls, breg, out, 64);
}

// Round 5
// 425.528 us; speedup vs baseline: 1.5622x; 1.3766x over previous
//
#include <hip/hip_runtime.h>

// ---------------------------------------------------------------------------
// FastRCNN head: RoIPool + FC(25088->4096) + FC(4096->4096) + heads (21/84).
// R5 = R4 structure with the B-LDS swizzle reverted to the R3-validated
// BIJECTIVE form (2-bit XOR). R4's 3-bit XOR overflowed the 16-slot column
// field (non-bijective -> aliased writes -> wrong data).
// Structure: A-frags direct from global (A has zero cross-wave reuse; L2
// serves cross-block reuse via z-pinning). Only B staged in LDS (2x4KB),
// raw s_barrier + counted compiler waits (no vmcnt(0) drain), B loads 2-deep.
// ---------------------------------------------------------------------------

typedef __attribute__((ext_vector_type(8))) __bf16 bf16x8;
typedef __attribute__((ext_vector_type(4))) float f32x4;

#define N_ROIS 512
#define FH 50
#define FW 50
#define KK1 25088      // 512*49
#define D1 4096

#define BM 512
#define BN 64
#define BK 32

// ---------------------------------------------------------------------------
// RoIPool: block = (roi, channel-group of 64). 4096 blocks -> full occupancy.
// ---------------------------------------------------------------------------
__global__ __launch_bounds__(256) void roipool_kernel(
    const float* __restrict__ x, const float* __restrict__ rois,
    __bf16* __restrict__ pooled) {
  const int bid = blockIdx.x;
  const int roi = bid >> 3;
  const int cg = bid & 7;
  const float s = 0.0625f;
  const float r0 = rois[roi * 4 + 0], r1 = rois[roi * 4 + 1];
  const float r2 = rois[roi * 4 + 2], r3 = rois[roi * 4 + 3];
  int x1 = (int)(r0 * s); x1 = min(max(x1, 0), FW - 1);
  int y1 = (int)(r1 * s); y1 = min(max(y1, 0), FH - 1);
  int x2 = (int)(r2 * s); x2 = min(max(x2, 0), FW - 1);
  int y2 = (int)(r3 * s); y2 = min(max(y2, 0), FH - 1);
  const int ww = x2 - x1 + 1, hh = y2 - y1 + 1;
  __shared__ int cs[7], ce[7], rs[7], re[7];
  if (threadIdx.x < 7) {
    int i = threadIdx.x;
    cs[i] = x1 + (i * ww) / 7;
    ce[i] = x1 + ((i + 1) * ww + 6) / 7;
    rs[i] = y1 + (i * hh) / 7;
    re[i] = y1 + ((i + 1) * hh + 6) / 7;
  }
  __syncthreads();
  for (int idx = threadIdx.x; idx < 64 * 49; idx += 256) {
    int cl = idx / 49;
    int p = idx - cl * 49;
    int py = p / 7, px = p - py * 7;
    const int c = cg * 64 + cl;
    const float* base = x + (size_t)c * (FH * FW);
    float m = -3.402823466e38f;
    for (int y = rs[py]; y < re[py]; ++y) {
      const float* rowp = base + y * FW;
      for (int xx = cs[px]; xx < ce[px]; ++xx) m = fmaxf(m, rowp[xx]);
    }
    pooled[(size_t)roi * KK1 + c * 49 + p] = (__bf16)m;
  }
}

// ---------------------------------------------------------------------------
// GEMM: part[z][512][npad] = A[512,K](bf16) @ B[K,N](fp32 -> bf16 at stage)
// z = bid & ((1<<zshift)-1) (XCD-pins K-windows), n0 = (bid>>zshift)*64.
// A: 4 x global_load_dwordx4 per wave-iter, straight to registers.
// B: reg-staged 2-deep; pair-packed bf16 in LDS. BIJECTIVE swizzle:
//    u32 idx = c*16 + ((kp>>2) ^ ((c>>2)&3))*4 + (kp&3)    [R3-validated]
//    read: 16B at c*64 + (ks ^ ((c>>2)&3))*16.
// Sync: lgkmcnt(0) + raw s_barrier per iter; no vmcnt(0) drain anywhere.
// ---------------------------------------------------------------------------
template <typename OutT>
__global__ __launch_bounds__(512, 4) void gemm_kernel(
    const __bf16* __restrict__ A, const float* __restrict__ B,
    OutT* __restrict__ part, int N, int K, int kslice, int npad, int zshift) {
  __shared__ unsigned int Bu[2][1024];  // 2 x 4KB
  const int tid = threadIdx.x;
  const int lane = tid & 63;
  const int w = tid >> 6;
  const int bid = blockIdx.x;
  const int z = bid & ((1 << zshift) - 1);
  const int n0 = (bid >> zshift) * BN;
  const int kbeg = z * kslice;
  const int niters = kslice / BK;  // always even here
  const bool fullN = (n0 + BN) <= N;

  const int fr = lane & 15;
  const int ks = lane >> 4;

  f32x4 acc[4][4];
#pragma unroll
  for (int i = 0; i < 4; ++i)
#pragma unroll
    for (int j = 0; j < 4; ++j) acc[i][j] = (f32x4){0.f, 0.f, 0.f, 0.f};

  // A: lane reads row w*64 + mf*16 + fr, 16B at k = kbeg + it*32 + ks*8
  const __bf16* Arow = A + (size_t)(w * 64 + fr) * K + kbeg + ks * 8;

  // B staging addresses (bijective 2-bit XOR swizzle, R3-validated)
  const int bkp = tid >> 5;           // k-pair 0..15
  const int bc0 = (tid & 31) * 2;     // col 0..62 even
  const int bgi = bkp >> 2, bei = bkp & 3;
  const int bidx0 = bc0 * 16 + ((bgi ^ ((bc0 >> 2) & 3)) << 2) + bei;
  const int bidx1 = (bc0 + 1) * 16 + ((bgi ^ (((bc0 + 1) >> 2) & 3)) << 2) + bei;
  const int kmaxB = kbeg + kslice;

  float2 blA0, blA1, blB0, blB1;  // 2-deep ping-pong (static names, rule #20)

  auto loadB = [&](int t, float2& r0v, float2& r1v) {
    int kg = kbeg + t * BK;
    if (kg >= kmaxB) kg = kbeg;  // clamped dup; values never consumed
    const float* g0 = B + (size_t)(kg + 2 * bkp) * N;
    if (fullN) {
      r0v = *(const float2*)(g0 + n0 + bc0);
      r1v = *(const float2*)(g0 + N + n0 + bc0);
    } else {
      const int c0 = n0 + bc0, c1 = c0 + 1;
      const float* g1 = g0 + N;
      r0v.x = (c0 < N) ? g0[c0] : 0.f;
      r0v.y = (c1 < N) ? g0[c1] : 0.f;
      r1v.x = (c0 < N) ? g1[c0] : 0.f;
      r1v.y = (c1 < N) ? g1[c1] : 0.f;
    }
  };
  auto writeB = [&](int buf, const float2& r0v, const float2& r1v) {
    union { __bf16 h[2]; unsigned int u; } p0, p1;
    p0.h[0] = (__bf16)r0v.x; p0.h[1] = (__bf16)r1v.x;  // lo = even k
    p1.h[0] = (__bf16)r0v.y; p1.h[1] = (__bf16)r1v.y;
    Bu[buf][bidx0] = p0.u;
    Bu[buf][bidx1] = p1.u;
  };

  // prologue: tiles 0 and 1 in flight; tile 0 written
  loadB(0, blA0, blA1);
  loadB(1, blB0, blB1);
  writeB(0, blA0, blA1);

  auto body = [&](int it, bool even) {
    // A frags for this iter (oldest vmem -> compiler counted-waits at MFMA)
    bf16x8 af0, af1, af2, af3;
    const __bf16* ap = Arow + it * BK;
    af0 = *(const bf16x8*)(ap);
    af1 = *(const bf16x8*)(ap + (size_t)16 * K);
    af2 = *(const bf16x8*)(ap + (size_t)32 * K);
    af3 = *(const bf16x8*)(ap + (size_t)48 * K);
    // B tile it+2 into the reg pair consumed by writeB at iter it+1
    if (even) loadB(it + 2, blA0, blA1);
    else      loadB(it + 2, blB0, blB1);
    // my ds ops (reads of prev iter, writes of tile it) complete -> barrier
    asm volatile("s_waitcnt lgkmcnt(0)" ::: "memory");
    __builtin_amdgcn_s_barrier();
    __builtin_amdgcn_sched_barrier(0);
    // write tile it+1 (compiler inserts counted vmcnt for the bl regs)
    if (it + 1 < niters) {
      if (even) writeB((it + 1) & 1, blB0, blB1);
      else      writeB((it + 1) & 1, blA0, blA1);
    }
    // B frags + MFMA
#pragma unroll
    for (int nf = 0; nf < 4; ++nf) {
      const int c = nf * 16 + fr;
      const int slot = ks ^ ((c >> 2) & 3);
      bf16x8 bfr =
          *(const bf16x8*)((const char*)&Bu[it & 1][0] + c * 64 + slot * 16);
      acc[0][nf] = __builtin_amdgcn_mfma_f32_16x16x32_bf16(af0, bfr, acc[0][nf], 0, 0, 0);
      acc[1][nf] = __builtin_amdgcn_mfma_f32_16x16x32_bf16(af1, bfr, acc[1][nf], 0, 0, 0);
      acc[2][nf] = __builtin_amdgcn_mfma_f32_16x16x32_bf16(af2, bfr, acc[2][nf], 0, 0, 0);
      acc[3][nf] = __builtin_amdgcn_mfma_f32_16x16x32_bf16(af3, bfr, acc[3][nf], 0, 0, 0);
    }
  };

  for (int it = 0; it < niters; it += 2) {
    body(it, true);
    body(it + 1, false);
  }

  // epilogue: C/D layout col = lane&15, row = (lane>>4)*4 + r
  const int r0 = ks * 4;
  OutT* pbase = part + (size_t)z * 512 * npad;
#pragma unroll
  for (int mf = 0; mf < 4; ++mf)
#pragma unroll
    for (int nf = 0; nf < 4; ++nf) {
      const int col = n0 + nf * 16 + fr;
#pragma unroll
      for (int r = 0; r < 4; ++r) {
        const int row = w * 64 + mf * 16 + r0 + r;
        pbase[(size_t)row * npad + col] = (OutT)acc[mf][nf][r];
      }
    }
}

// sum bf16 split-K partials + bias, relu -> bf16 activations [512][4096]
__global__ __launch_bounds__(256) void reduce_relu_kernel(
    const __bf16* __restrict__ part, const float* __restrict__ bias,
    __bf16* __restrict__ out, int nsplit) {
  const int idx = blockIdx.x * 256 + threadIdx.x;
  const int flat = idx * 8;
  if (flat >= 512 * 4096) return;
  float s[8];
#pragma unroll
  for (int j = 0; j < 8; ++j) s[j] = 0.f;
  for (int sp = 0; sp < nsplit; ++sp) {
    bf16x8 v = *(const bf16x8*)(part + (size_t)sp * (512 * 4096) + flat);
#pragma unroll
    for (int j = 0; j < 8; ++j) s[j] += (float)v[j];
  }
  const int nb = flat & 4095;
  bf16x8 o;
#pragma unroll
  for (int j = 0; j < 8; ++j) {
    float v = s[j] + bias[nb + j];
    o[j] = (__bf16)(v > 0.f ? v : 0.f);
  }
  *(bf16x8*)(out + flat) = o;
}

// final: sum split-K fp32 partials + bias -> d_out fp32 (cls then reg)
__global__ __launch_bounds__(256) void reduce_out_kernel(
    const float* __restrict__ pc, const float* __restrict__ pr,
    const float* __restrict__ bcls, const float* __restrict__ breg,
    float* __restrict__ out, int nsplit) {
  const int gid = blockIdx.x * 256 + threadIdx.x;
  if (gid >= 512 * 105) return;
  if (gid < 512 * 21) {
    const int m = gid / 21, j = gid - m * 21;
    float s = bcls[j];
    for (int sp = 0; sp < nsplit; ++sp)
      s += pc[(size_t)sp * 512 * 64 + m * 64 + j];
    out[gid] = s;
  } else {
    const int g = gid - 512 * 21;
    const int m = g / 84, j = g - m * 84;
    float s = breg[j];
    for (int sp = 0; sp < nsplit; ++sp)
      s += pr[(size_t)sp * 512 * 128 + m * 128 + j];
    out[gid] = s;
  }
}

extern "C" void kernel_launch(void* const* d_in, const int* in_sizes, int n_in,
                              void* d_out, int out_size, void* d_ws, size_t ws_size,
                              hipStream_t stream) {
  (void)in_sizes; (void)n_in; (void)out_size;
  const float* x    = (const float*)d_in[0];
  const float* rois = (const float*)d_in[2];
  const float* W1   = (const float*)d_in[3];
  const float* b1   = (const float*)d_in[4];
  const float* W2   = (const float*)d_in[5];
  const float* b2   = (const float*)d_in[6];
  const float* Wcls = (const float*)d_in[7];
  const float* bcls = (const float*)d_in[8];
  const float* Wreg = (const float*)d_in[9];
  const float* breg = (const float*)d_in[10];
  float* out = (float*)d_out;

  const size_t pooled_b = (size_t)512 * KK1 * 2;        // 25,690,112
  const size_t act_b = (size_t)512 * D1 * 2;            // 4 MiB
  const size_t need8 = pooled_b + (size_t)8 * act_b + 2 * act_b;
  const int ns = (ws_size >= need8) ? 8 : 2;            // ns=8 confirmed runs
  const int zshift = (ns == 8) ? 3 : 1;

  char* ws = (char*)d_ws;
  __bf16* pooled = (__bf16*)ws;
  __bf16* part1 = (__bf16*)(ws + pooled_b);             // ns * 4MiB
  __bf16* f1 = (__bf16*)(ws + pooled_b + (size_t)ns * act_b);
  __bf16* f2 = (__bf16*)(ws + pooled_b + (size_t)ns * act_b + act_b);
  __bf16* part2 = (__bf16*)ws;                          // alias dead pooled+part1
  float* pcls = (float*)ws;                             // heads phase aliases
  float* preg = (float*)(ws + (size_t)64 * 512 * 64 * 4);  // +8.4MB

  // 1) RoIPool -> pooled bf16 [512, 25088]; 4096 blocks for occupancy
  roipool_kernel<<<N_ROIS * 8, 256, 0, stream>>>(x, rois, pooled);

  // 2) GEMM1: pooled @ W1[25088,4096]; W1 read exactly once; z-pinned XCDs
  gemm_kernel<__bf16><<<64 * ns, 512, 0, stream>>>(
      pooled, W1, part1, 4096, KK1, KK1 / ns, 4096, zshift);
  reduce_relu_kernel<<<1024, 256, 0, stream>>>(part1, b1, f1, ns);

  // 3) GEMM2: f1 @ W2[4096,4096]
  gemm_kernel<__bf16><<<64 * ns, 512, 0, stream>>>(
      f1, W2, part2, 4096, 4096, 4096 / ns, 4096, zshift);
  reduce_relu_kernel<<<1024, 256, 0, stream>>>(part2, b2, f2, ns);

  // 4) heads: split-K=64 (zshift 6): grids 64 / 128 blocks
  gemm_kernel<float><<<1 * 64, 512, 0, stream>>>(
      f2, Wcls, pcls, 21, 4096, 64, 64, 6);
  gemm_kernel<float><<<2 * 64, 512, 0, stream>>>(
      f2, Wreg, preg, 84, 4096, 64, 128, 6);
  reduce_out_kernel<<<(512 * 105 + 255) / 256, 256, 0, stream>>>(
      pcls, preg, bcls, breg, out, 64);
}